// Round 6
// baseline (490.868 us; speedup 1.0000x reference)
//
#include <hip/hip_runtime.h>
#include <hip/hip_bf16.h>

typedef unsigned short u16;
typedef __attribute__((ext_vector_type(4))) short short4v;
typedef __attribute__((ext_vector_type(8))) short short8;
typedef __attribute__((ext_vector_type(4))) float float4v;
typedef __attribute__((ext_vector_type(16))) float f32x16;

__device__ __forceinline__ void async_copy16(const void* g, void* l) {
  // HW-validated (r2 vs r3 bit-identity): 16B/lane global->LDS DMA
  __builtin_amdgcn_global_load_lds(
      (const __attribute__((address_space(1))) unsigned int*)g,
      (__attribute__((address_space(3))) unsigned int*)l,
      16, 0, 0);
}

__device__ __forceinline__ u16 f2bf(float f) {
  __hip_bfloat16 h = __float2bfloat16(f);  // RNE
  return *reinterpret_cast<u16*>(&h);
}

__device__ __forceinline__ unsigned pack2(float a, float b) {
  return (unsigned)f2bf(a) | ((unsigned)f2bf(b) << 16);
}

// native 2^x: v_exp_f32 computes 2^S0 (ISA). __exp2f doesn't exist in HIP.
__device__ __forceinline__ float exp2_fast(float x) {
  return __builtin_amdgcn_exp2f(x);
}

// ---------------- fp32 -> bf16 conversion pass ----------------
struct CArgs {
  const float* in[7];
  u16* out[7];
  int n[7];
};

__global__ void conv_bf16(CArgs a) {
  int t = blockIdx.y;
  int n = a.n[t];
  long i = ((long)blockIdx.x * blockDim.x + threadIdx.x) * 8;
  if (i >= n) return;
  const float4v* f = (const float4v*)(a.in[t] + i);
  float4v lo = f[0], hi = f[1];
  u16 o[8];
  o[0] = f2bf(lo.x); o[1] = f2bf(lo.y); o[2] = f2bf(lo.z); o[3] = f2bf(lo.w);
  o[4] = f2bf(hi.x); o[5] = f2bf(hi.y); o[6] = f2bf(hi.z); o[7] = f2bf(hi.w);
  *(short8*)(a.out[t] + i) = *(const short8*)o;
}

// ---------------- GEMM (m97 single-buffer): C = A*W^T + b -------------------
// r5's 2-phase dbuf was the guide-documented NULL (m99/m100) and measured
// net-negative here -> reverted. launch_bounds(256,3) caps VGPR at 168
// (m97's 164 fits) -> 3 resident blocks/CU, matching the 912 TF reference
// config; (256,2) let the allocator balloon regs -> 2 blocks/CU.
// A,W bf16 [.,K] row-major; bias fp32. mode 0: fp32 C[m*N+n];
// mode 1: bf16 (b,h,s,dh); mode 2: bf16 (b,h,dh,s) transposed
template <bool OUT_F32>
__device__ __forceinline__
void gemm_body(const u16* __restrict__ A, const u16* __restrict__ W,
               const float* __restrict__ bias, void* __restrict__ Cp,
               int M, int N, int K, int mode) {
  __shared__ __attribute__((aligned(16))) u16 As[128 * 32];
  __shared__ __attribute__((aligned(16))) u16 Ws[128 * 32];

  const int tid  = threadIdx.x;
  const int lane = tid & 63;
  const int wave = tid >> 6;
  const int ln15 = lane & 15;
  const int quad = lane >> 4;
  const int m0 = blockIdx.y * 128;
  const int n0 = blockIdx.x * 128;
  const int wm = (wave & 1) * 64;
  const int wn = (wave >> 1) * 64;

  float4v acc[4][4];
#pragma unroll
  for (int i = 0; i < 4; i++)
#pragma unroll
    for (int j = 0; j < 4; j++) acc[i][j] = (float4v)0.0f;

  for (int k0 = 0; k0 < K; k0 += 32) {
#pragma unroll
    for (int c = 0; c < 2; c++) {
      int e = (c * 256 + tid) * 8;
      int r = e >> 5, col = e & 31;
      async_copy16(A + (size_t)(m0 + r) * K + k0 + col, (void*)(As + e));
      async_copy16(W + (size_t)(n0 + r) * K + k0 + col, (void*)(Ws + e));
    }
    __syncthreads();

    short8 af[4], bfr[4];
#pragma unroll
    for (int i = 0; i < 4; i++)
      af[i] = *(const short8*)(As + (wm + i * 16 + ln15) * 32 + quad * 8);
#pragma unroll
    for (int j = 0; j < 4; j++)
      bfr[j] = *(const short8*)(Ws + (wn + j * 16 + ln15) * 32 + quad * 8);
#pragma unroll
    for (int i = 0; i < 4; i++)
#pragma unroll
      for (int j = 0; j < 4; j++)
        acc[i][j] = __builtin_amdgcn_mfma_f32_16x16x32_bf16(af[i], bfr[j], acc[i][j], 0, 0, 0);
    __syncthreads();
  }

  // epilogue; C/D layout: col = lane&15, row = quad*4 + reg (HW-verified)
#pragma unroll
  for (int j = 0; j < 4; j++) {
    int n = n0 + wn + j * 16 + ln15;
    float bval = bias[n];
#pragma unroll
    for (int i = 0; i < 4; i++) {
#pragma unroll
      for (int r = 0; r < 4; r++) {
        int m = m0 + wm + i * 16 + quad * 4 + r;
        float v = acc[i][j][r] + bval;
        size_t addr;
        if (mode == 0) {
          addr = (size_t)m * N + n;
        } else {
          int b = m >> 11, s = m & 2047;
          int h = n >> 6, dh = n & 63;
          if (mode == 1) addr = (((size_t)(b * 16 + h)) * 2048 + s) * 64 + dh;
          else           addr = (((size_t)(b * 16 + h)) * 64 + dh) * 2048 + s;
        }
        if (OUT_F32) ((float*)Cp)[addr] = v;
        else         ((u16*)Cp)[addr] = f2bf(v);
      }
    }
  }
}

template <bool OUT_F32>
__global__ __launch_bounds__(256, 3)
void gemm_bt(const u16* __restrict__ A, const u16* __restrict__ W,
             const float* __restrict__ bias, void* __restrict__ Cp,
             int M, int N, int K, int mode) {
  gemm_body<OUT_F32>(A, W, bias, Cp, M, N, K, mode);
}

// z-batched Q/K/V projections: one launch, 1536 blocks, no inter-launch gaps.
struct G3 {
  const u16* A[3]; const u16* W[3]; const float* bias[3];
  void* C[3]; int mode[3];
};

__global__ __launch_bounds__(256, 3)
void gemm_qkv(G3 g) {
  const int z = blockIdx.z;
  gemm_body<false>(g.A[z], g.W[z], g.bias[z], g.C[z], 8192, 1024, 1024, g.mode[z]);
}

// ---------------- Flash attention (32x32 MFMA, T12 permlane, 2-way ILP) ----
// Q,K: (b,h,s,dh) bf16 ; Vt: (b,h,dh,s) bf16 ; mask: (B,1,S) int32
// out Ct (concat): (b, s, h*64+dh) bf16
//
// S^T = mfma_32x32x16(K, Q): D col = q = lane&31 (fixed per lane!),
// row = k = (reg&3) + 8*(reg>>2) + 4*(lane>>5)  [m74/m101 HW-verified].
// r5 diagnosis: latency-bound (MfmaUtil 21, VALU 50, occ 35) with 4-deep
// serial MFMA accumulation chains. This round: break chains ->
//   QK: two 2-deep chains sA/sB, summed (32 extra v_add/tile)
//   PV: accA (kb=0) / accB (kb=1), four 2-deep chains, summed ONCE in
//       epilogue (+32 VGPR, zero per-tile cost).
// launch_bounds(256,3): cap 168; actual ~105-115 -> still 4 blocks/CU
// (residency follows actual VGPR count; the bound is an allocator cap).
#define SWZ(c, r) ((c) ^ (((r) & 7) << 3))
__global__ __launch_bounds__(256, 3)
void attn(const u16* __restrict__ Q, const u16* __restrict__ K,
          const u16* __restrict__ Vt, const int* __restrict__ mask,
          u16* __restrict__ Ct) {
  __shared__ __attribute__((aligned(16))) u16 Ks[2][64 * 64];
  __shared__ __attribute__((aligned(16))) u16 Vs[2][64 * 64];

  const int tid  = threadIdx.x;
  const int lane = tid & 63;
  const int wave = tid >> 6;
  const int ln31 = lane & 31;
  const int hi   = lane >> 5;
  const int bh = blockIdx.y;
  const int b = bh >> 4, h = bh & 15;
  const int q0 = blockIdx.x * 128;
  const int qr0 = wave * 32;

  const u16* Qg = Q + ((size_t)bh * 2048 + q0 + qr0) * 64;
  const u16* Kg = K + (size_t)bh * 2048 * 64;
  const u16* Vg = Vt + (size_t)bh * 64 * 2048;
  const int* mg = mask + b * 2048;

  const float C2 = 0.04508422f;  // log2(e)/32

  // hoist Q fragments: qf[m] = Q[q = ln31][dh = m*16 + hi*8 .. +8]
  short8 qf[4];
#pragma unroll
  for (int m = 0; m < 4; m++)
    qf[m] = *(const short8*)(Qg + (size_t)ln31 * 64 + m * 16 + hi * 8);

  // stage K/V tile 0 into buf 0 (swizzled)
#pragma unroll
  for (int c = 0; c < 2; c++) {
    int e = (c * 256 + tid) * 8;
    int r = e >> 6, col = e & 63;
    int sc = SWZ(col, r);
    *(short8*)(Ks[0] + r * 64 + sc) = *(const short8*)(Kg + (size_t)r * 64 + col);
    *(short8*)(Vs[0] + r * 64 + sc) = *(const short8*)(Vg + (size_t)r * 2048 + col);
  }

  // ctx^T accumulators: accA (kb=0 halves), accB (kb=1 halves); summed at end.
  f32x16 accA[2], accB[2];
#pragma unroll
  for (int d = 0; d < 2; d++) { accA[d] = (f32x16)0.0f; accB[d] = (f32x16)0.0f; }
  float lrow = 0.0f;  // per-lane denom partial for q = ln31

  for (int t = 0; t < 32; t++) {
    const int buf = t & 1;
    __syncthreads();

    // prefetch next K/V tile into registers (in flight during QK^T)
    short8 kreg[2], vreg[2];
    const bool havenext = (t + 1) < 32;
    if (havenext) {
      int kt2 = (t + 1) * 64;
#pragma unroll
      for (int c = 0; c < 2; c++) {
        int e = (c * 256 + tid) * 8;
        int r = e >> 6, col = e & 63;
        kreg[c] = *(const short8*)(Kg + (size_t)(kt2 + r) * 64 + col);
        vreg[c] = *(const short8*)(Vg + (size_t)r * 2048 + kt2 + col);
      }
    }

    // Per k-half kb (32 keys): S^T = K*Q^T (two 2-deep mfma chains), exp2,
    // pack, permlane.
    unsigned bw[2][2][4];
#pragma unroll
    for (int kb = 0; kb < 2; kb++) {
      const int krow = kb * 32 + ln31;
      short8 kf0 = *(const short8*)(Ks[buf] + krow * 64 + SWZ(0 * 16 + hi * 8, krow));
      short8 kf1 = *(const short8*)(Ks[buf] + krow * 64 + SWZ(1 * 16 + hi * 8, krow));
      short8 kf2 = *(const short8*)(Ks[buf] + krow * 64 + SWZ(2 * 16 + hi * 8, krow));
      short8 kf3 = *(const short8*)(Ks[buf] + krow * 64 + SWZ(3 * 16 + hi * 8, krow));
      f32x16 sA = (f32x16)0.0f, sB = (f32x16)0.0f;
      __builtin_amdgcn_s_setprio(1);
      sA = __builtin_amdgcn_mfma_f32_32x32x16_bf16(kf0, qf[0], sA, 0, 0, 0);
      sB = __builtin_amdgcn_mfma_f32_32x32x16_bf16(kf1, qf[1], sB, 0, 0, 0);
      sA = __builtin_amdgcn_mfma_f32_32x32x16_bf16(kf2, qf[2], sA, 0, 0, 0);
      sB = __builtin_amdgcn_mfma_f32_32x32x16_bf16(kf3, qf[3], sB, 0, 0, 0);
      __builtin_amdgcn_s_setprio(0);
      f32x16 s = sA + sB;
      // s[reg] is for k(in-tile) = kb*32 + 8*(reg>>2) + 4*hi + (reg&3)
      unsigned w[8];
#pragma unroll
      for (int g = 0; g < 4; g++) {
        int4 m4 = *(const int4*)(mg + t * 64 + kb * 32 + g * 8 + hi * 4);
        float mb0 = (m4.x == 0) ? -1.5e30f : 0.0f;
        float mb1 = (m4.y == 0) ? -1.5e30f : 0.0f;
        float mb2 = (m4.z == 0) ? -1.5e30f : 0.0f;
        float mb3 = (m4.w == 0) ? -1.5e30f : 0.0f;
        float p0 = exp2_fast(fmaf(s[4 * g + 0], C2, mb0));
        float p1 = exp2_fast(fmaf(s[4 * g + 1], C2, mb1));
        float p2 = exp2_fast(fmaf(s[4 * g + 2], C2, mb2));
        float p3 = exp2_fast(fmaf(s[4 * g + 3], C2, mb3));
        lrow += (p0 + p1) + (p2 + p3);
        w[2 * g]     = pack2(p0, p1);
        w[2 * g + 1] = pack2(p2, p3);
      }
      // permlane32_swap pairing w[g] with w[g+2] (+8 k) yields both halves (T12)
#pragma unroll
      for (int c = 0; c < 2; c++) {
        auto r0 = __builtin_amdgcn_permlane32_swap(w[c], w[2 + c], false, false);
        bw[kb][0][c]     = r0[0];
        bw[kb][0][2 + c] = r0[1];
        auto r1 = __builtin_amdgcn_permlane32_swap(w[4 + c], w[6 + c], false, false);
        bw[kb][1][c]     = r1[0];
        bw[kb][1][2 + c] = r1[1];
      }
    }

    // write prefetched tile to the other buffer (visible after next barrier)
    if (havenext) {
#pragma unroll
      for (int c = 0; c < 2; c++) {
        int e = (c * 256 + tid) * 8;
        int r = e >> 6, col = e & 63;
        int sc = SWZ(col, r);
        *(short8*)(Ks[buf ^ 1] + r * 64 + sc) = kreg[c];
        *(short8*)(Vs[buf ^ 1] + r * 64 + sc) = vreg[c];
      }
    }

    // ctx^T += V^T * P^T: 8 mfma as FOUR independent 2-deep chains
    // (accA[d] <- kb=0 mp=0,1 ; accB[d] <- kb=1 mp=0,1)
    __builtin_amdgcn_s_setprio(1);
#pragma unroll
    for (int d = 0; d < 2; d++) {
      const int vrow = d * 32 + ln31;
#pragma unroll
      for (int mp = 0; mp < 2; mp++) {
        {
          short8 vf = *(const short8*)(Vs[buf] + vrow * 64 + SWZ(0 * 32 + mp * 16 + hi * 8, vrow));
          union { unsigned w4[4]; short8 s8; } u;
          u.w4[0] = bw[0][mp][0]; u.w4[1] = bw[0][mp][1];
          u.w4[2] = bw[0][mp][2]; u.w4[3] = bw[0][mp][3];
          accA[d] = __builtin_amdgcn_mfma_f32_32x32x16_bf16(vf, u.s8, accA[d], 0, 0, 0);
        }
        {
          short8 vf = *(const short8*)(Vs[buf] + vrow * 64 + SWZ(1 * 32 + mp * 16 + hi * 8, vrow));
          union { unsigned w4[4]; short8 s8; } u;
          u.w4[0] = bw[1][mp][0]; u.w4[1] = bw[1][mp][1];
          u.w4[2] = bw[1][mp][2]; u.w4[3] = bw[1][mp][3];
          accB[d] = __builtin_amdgcn_mfma_f32_32x32x16_bf16(vf, u.s8, accB[d], 0, 0, 0);
        }
      }
    }
    __builtin_amdgcn_s_setprio(0);
  }

  // epilogue: finish denom (lanes l, l^32 share q), scale, packed 8B stores.
  // acc[d][reg]: dh = d*32 + 8*(reg>>2) + 4*hi + (reg&3), q = ln31.
  float l = lrow + __shfl_xor(lrow, 32);
  float inv = 1.0f / l;
  const int s = q0 + qr0 + ln31;
  u16* base = Ct + ((size_t)(b * 2048 + s)) * 1024 + h * 64 + hi * 4;
#pragma unroll
  for (int d = 0; d < 2; d++) {
    f32x16 acc = accA[d] + accB[d];
#pragma unroll
    for (int g = 0; g < 4; g++) {
      u16 o[4];
      o[0] = f2bf(acc[4 * g + 0] * inv);
      o[1] = f2bf(acc[4 * g + 1] * inv);
      o[2] = f2bf(acc[4 * g + 2] * inv);
      o[3] = f2bf(acc[4 * g + 3] * inv);
      *(short4v*)(base + d * 32 + g * 8) = *(const short4v*)o;
    }
  }
}

// ---------------- launch ----------------

extern "C" void kernel_launch(void* const* d_in, const int* in_sizes, int n_in,
                              void* d_out, int out_size, void* d_ws, size_t ws_size,
                              hipStream_t stream) {
  int iq, ik, iv, im, iWq, ibq, iWk, ibk, iWv, ibv, iWo, ibo;
  if (in_sizes[0] == 8388608) {  // dict order: query first
    iq = 0; ik = 1; iv = 2; im = 3;
    iWq = 4; ibq = 5; iWk = 6; ibk = 7; iWv = 8; ibv = 9; iWo = 10; ibo = 11;
  } else {                        // alphabetical fallback
    iWk = 0; iWo = 1; iWq = 2; iWv = 3;
    ibk = 4; ibo = 5; ibq = 6; ibv = 7;
    ik = 8; im = 9; iq = 10; iv = 11;
  }
  const float* query = (const float*)d_in[iq];
  const float* key   = (const float*)d_in[ik];
  const float* value = (const float*)d_in[iv];
  const int*   mask  = (const int*)d_in[im];
  const float* Wq = (const float*)d_in[iWq];
  const float* bq = (const float*)d_in[ibq];
  const float* Wk = (const float*)d_in[iWk];
  const float* bk = (const float*)d_in[ibk];
  const float* Wv = (const float*)d_in[iWv];
  const float* bv = (const float*)d_in[ibv];
  const float* Wo = (const float*)d_in[iWo];
  const float* bo = (const float*)d_in[ibo];

  const long U  = 8388608;   // 4*2048*1024
  const long Wn = 1048576;   // 1024*1024
  u16* ws = (u16*)d_ws;
  u16* cq   = ws;            // bf16 query          16.8 MB
  u16* ck   = cq + U;        // bf16 key            16.8 MB
  u16* cv   = ck + U;        // bf16 value          16.8 MB
  u16* cWq  = cv + U;        // bf16 weights         2.1 MB x4
  u16* cWk  = cWq + Wn;
  u16* cWv  = cWk + Wn;
  u16* cWo  = cWv + Wn;
  u16* qws  = cWo + Wn;      // Q (b,h,s,dh)        16.8 MB
  u16* kws  = qws + U;       // K (b,h,s,dh)        16.8 MB
  u16* cws  = ck;            // alias: ck dead once attn runs (post-GEMMs)

  // Batched QKV needs V's output distinct from cq (Q-proj reads cq
  // concurrently). Take a fresh region if the workspace allows; else fall
  // back to the validated sequential path with vtws aliasing cq.
  const size_t need_batched = (size_t)(7 * U + 4 * Wn) * sizeof(u16);  // 109 MB
  const bool batched = ws_size >= need_batched;
  u16* vtws = batched ? (kws + U) : cq;   // V^T (b,h,dh,s)  16.8 MB

  dim3 blk(256);

  CArgs ca;
  ca.in[0] = query; ca.out[0] = cq;  ca.n[0] = (int)U;
  ca.in[1] = key;   ca.out[1] = ck;  ca.n[1] = (int)U;
  ca.in[2] = value; ca.out[2] = cv;  ca.n[2] = (int)U;
  ca.in[3] = Wq;    ca.out[3] = cWq; ca.n[3] = (int)Wn;
  ca.in[4] = Wk;    ca.out[4] = cWk; ca.n[4] = (int)Wn;
  ca.in[5] = Wv;    ca.out[5] = cWv; ca.n[5] = (int)Wn;
  ca.in[6] = Wo;    ca.out[6] = cWo; ca.n[6] = (int)Wn;
  conv_bf16<<<dim3(4096, 7), blk, 0, stream>>>(ca);

  dim3 gproj(8, 64);  // N/128 x M/128
  if (batched) {
    G3 g3;
    g3.A[0] = cq; g3.W[0] = cWq; g3.bias[0] = bq; g3.C[0] = qws;  g3.mode[0] = 1;
    g3.A[1] = ck; g3.W[1] = cWk; g3.bias[1] = bk; g3.C[1] = kws;  g3.mode[1] = 1;
    g3.A[2] = cv; g3.W[2] = cWv; g3.bias[2] = bv; g3.C[2] = vtws; g3.mode[2] = 2;
    gemm_qkv<<<dim3(8, 64, 3), blk, 0, stream>>>(g3);
  } else {
    gemm_bt<false><<<gproj, blk, 0, stream>>>(cq, cWq, bq, qws, 8192, 1024, 1024, 1);
    gemm_bt<false><<<gproj, blk, 0, stream>>>(ck, cWk, bk, kws, 8192, 1024, 1024, 1);
    gemm_bt<false><<<gproj, blk, 0, stream>>>(cv, cWv, bv, vtws, 8192, 1024, 1024, 2);
  }
  attn<<<dim3(16, 64), blk, 0, stream>>>(qws, kws, vtws, mask, cws);
  gemm_bt<true><<<gproj, blk, 0, stream>>>(cws, cWo, bo, d_out, 8192, 1024, 1024, 0);
}

// Round 7
// 429.155 us; speedup vs baseline: 1.1438x; 1.1438x over previous
//
#include <hip/hip_runtime.h>
#include <hip/hip_bf16.h>

typedef unsigned short u16;
typedef __attribute__((ext_vector_type(4))) short short4v;
typedef __attribute__((ext_vector_type(8))) short short8;
typedef __attribute__((ext_vector_type(4))) float float4v;
typedef __attribute__((ext_vector_type(16))) float f32x16;

__device__ __forceinline__ void async_copy16(const void* g, void* l) {
  // HW-validated (r2 vs r3 bit-identity): 16B/lane global->LDS DMA
  __builtin_amdgcn_global_load_lds(
      (const __attribute__((address_space(1))) unsigned int*)g,
      (__attribute__((address_space(3))) unsigned int*)l,
      16, 0, 0);
}

__device__ __forceinline__ u16 f2bf(float f) {
  __hip_bfloat16 h = __float2bfloat16(f);  // RNE
  return *reinterpret_cast<u16*>(&h);
}

__device__ __forceinline__ unsigned pack2(float a, float b) {
  return (unsigned)f2bf(a) | ((unsigned)f2bf(b) << 16);
}

// native 2^x: v_exp_f32 computes 2^S0 (ISA). __exp2f doesn't exist in HIP.
__device__ __forceinline__ float exp2_fast(float x) {
  return __builtin_amdgcn_exp2f(x);
}

// ---------------- fp32 -> bf16 conversion pass ----------------
struct CArgs {
  const float* in[7];
  u16* out[7];
  int n[7];
};

__global__ void conv_bf16(CArgs a) {
  int t = blockIdx.y;
  int n = a.n[t];
  long i = ((long)blockIdx.x * blockDim.x + threadIdx.x) * 8;
  if (i >= n) return;
  const float4v* f = (const float4v*)(a.in[t] + i);
  float4v lo = f[0], hi = f[1];
  u16 o[8];
  o[0] = f2bf(lo.x); o[1] = f2bf(lo.y); o[2] = f2bf(lo.z); o[3] = f2bf(lo.w);
  o[4] = f2bf(hi.x); o[5] = f2bf(hi.y); o[6] = f2bf(hi.z); o[7] = f2bf(hi.w);
  *(short8*)(a.out[t] + i) = *(const short8*)o;
}

// ---------------- GEMM (m97 single-buffer): C = A*W^T + b -------------------
// Best-measured GEMM stack (r6): single-buffer m97 body + launch_bounds
// (256,3) (VGPR cap 168; m97's 164 fits -> 3 resident blocks/CU). The r5
// 2-phase dbuf was the guide-documented NULL (m99/m100) and measured -16us
// worse here. DO NOT re-add dbuf at HIP source level.
// A,W bf16 [.,K] row-major; bias fp32. mode 0: fp32 C[m*N+n];
// mode 1: bf16 (b,h,s,dh); mode 2: bf16 (b,h,dh,s) transposed
template <bool OUT_F32>
__device__ __forceinline__
void gemm_body(const u16* __restrict__ A, const u16* __restrict__ W,
               const float* __restrict__ bias, void* __restrict__ Cp,
               int M, int N, int K, int mode) {
  __shared__ __attribute__((aligned(16))) u16 As[128 * 32];
  __shared__ __attribute__((aligned(16))) u16 Ws[128 * 32];

  const int tid  = threadIdx.x;
  const int lane = tid & 63;
  const int wave = tid >> 6;
  const int ln15 = lane & 15;
  const int quad = lane >> 4;
  const int m0 = blockIdx.y * 128;
  const int n0 = blockIdx.x * 128;
  const int wm = (wave & 1) * 64;
  const int wn = (wave >> 1) * 64;

  float4v acc[4][4];
#pragma unroll
  for (int i = 0; i < 4; i++)
#pragma unroll
    for (int j = 0; j < 4; j++) acc[i][j] = (float4v)0.0f;

  for (int k0 = 0; k0 < K; k0 += 32) {
#pragma unroll
    for (int c = 0; c < 2; c++) {
      int e = (c * 256 + tid) * 8;
      int r = e >> 5, col = e & 31;
      async_copy16(A + (size_t)(m0 + r) * K + k0 + col, (void*)(As + e));
      async_copy16(W + (size_t)(n0 + r) * K + k0 + col, (void*)(Ws + e));
    }
    __syncthreads();

    short8 af[4], bfr[4];
#pragma unroll
    for (int i = 0; i < 4; i++)
      af[i] = *(const short8*)(As + (wm + i * 16 + ln15) * 32 + quad * 8);
#pragma unroll
    for (int j = 0; j < 4; j++)
      bfr[j] = *(const short8*)(Ws + (wn + j * 16 + ln15) * 32 + quad * 8);
#pragma unroll
    for (int i = 0; i < 4; i++)
#pragma unroll
      for (int j = 0; j < 4; j++)
        acc[i][j] = __builtin_amdgcn_mfma_f32_16x16x32_bf16(af[i], bfr[j], acc[i][j], 0, 0, 0);
    __syncthreads();
  }

  // epilogue; C/D layout: col = lane&15, row = quad*4 + reg (HW-verified)
#pragma unroll
  for (int j = 0; j < 4; j++) {
    int n = n0 + wn + j * 16 + ln15;
    float bval = bias[n];
#pragma unroll
    for (int i = 0; i < 4; i++) {
#pragma unroll
      for (int r = 0; r < 4; r++) {
        int m = m0 + wm + i * 16 + quad * 4 + r;
        float v = acc[i][j][r] + bval;
        size_t addr;
        if (mode == 0) {
          addr = (size_t)m * N + n;
        } else {
          int b = m >> 11, s = m & 2047;
          int h = n >> 6, dh = n & 63;
          if (mode == 1) addr = (((size_t)(b * 16 + h)) * 2048 + s) * 64 + dh;
          else           addr = (((size_t)(b * 16 + h)) * 64 + dh) * 2048 + s;
        }
        if (OUT_F32) ((float*)Cp)[addr] = v;
        else         ((u16*)Cp)[addr] = f2bf(v);
      }
    }
  }
}

template <bool OUT_F32>
__global__ __launch_bounds__(256, 3)
void gemm_bt(const u16* __restrict__ A, const u16* __restrict__ W,
             const float* __restrict__ bias, void* __restrict__ Cp,
             int M, int N, int K, int mode) {
  gemm_body<OUT_F32>(A, W, bias, Cp, M, N, K, mode);
}

// z-batched Q/K/V projections: one launch, 1536 blocks, no inter-launch gaps.
struct G3 {
  const u16* A[3]; const u16* W[3]; const float* bias[3];
  void* C[3]; int mode[3];
};

__global__ __launch_bounds__(256, 3)
void gemm_qkv(G3 g) {
  const int z = blockIdx.z;
  gemm_body<false>(g.A[z], g.W[z], g.bias[z], g.C[z], 8192, 1024, 1024, g.mode[z]);
}

// ---------------- Flash attention (32x32 MFMA, T12 permlane repack) --------
// EXACT r5 kernel -- best measured attn this session: 141.0 us, VGPR 64,
// occ 34.9, MfmaUtil 20.8, zero spill. r6's accA/accB ILP split (+32 VGPR)
// spilled (WRITE 47MB) and lost 66us: in this kernel VGPR headroom beats
// MFMA-chain ILP (latency is hidden by 4 resident blocks, not ILP).
//
// S^T = mfma_32x32x16(K, Q): D col = q = lane&31 (fixed per lane!),
// row = k = (reg&3) + 8*(reg>>2) + 4*(lane>>5)  [m74/m101 HW-verified].
// P->B repack: 16 cvt_pk words + 8 permlane32_swap per KV-64 tile (T12).
// Softmax: p = exp2(fma(s, log2e/32, mb)) -- one fma + v_exp per element.
// Known debt: 32-row frag reads are structurally 4-way on the 8-slot XOR
// swizzle (8.39e6 conflict-cycles, ~9%).
#define SWZ(c, r) ((c) ^ (((r) & 7) << 3))
__global__ __launch_bounds__(256, 4)
void attn(const u16* __restrict__ Q, const u16* __restrict__ K,
          const u16* __restrict__ Vt, const int* __restrict__ mask,
          u16* __restrict__ Ct) {
  __shared__ __attribute__((aligned(16))) u16 Ks[2][64 * 64];
  __shared__ __attribute__((aligned(16))) u16 Vs[2][64 * 64];

  const int tid  = threadIdx.x;
  const int lane = tid & 63;
  const int wave = tid >> 6;
  const int ln31 = lane & 31;
  const int hi   = lane >> 5;
  const int bh = blockIdx.y;
  const int b = bh >> 4, h = bh & 15;
  const int q0 = blockIdx.x * 128;
  const int qr0 = wave * 32;

  const u16* Qg = Q + ((size_t)bh * 2048 + q0 + qr0) * 64;
  const u16* Kg = K + (size_t)bh * 2048 * 64;
  const u16* Vg = Vt + (size_t)bh * 64 * 2048;
  const int* mg = mask + b * 2048;

  const float C2 = 0.04508422f;  // log2(e)/32

  // hoist Q fragments: qf[m] = Q[q = ln31][dh = m*16 + hi*8 .. +8]
  short8 qf[4];
#pragma unroll
  for (int m = 0; m < 4; m++)
    qf[m] = *(const short8*)(Qg + (size_t)ln31 * 64 + m * 16 + hi * 8);

  // stage K/V tile 0 into buf 0 (swizzled)
#pragma unroll
  for (int c = 0; c < 2; c++) {
    int e = (c * 256 + tid) * 8;
    int r = e >> 6, col = e & 63;
    int sc = SWZ(col, r);
    *(short8*)(Ks[0] + r * 64 + sc) = *(const short8*)(Kg + (size_t)r * 64 + col);
    *(short8*)(Vs[0] + r * 64 + sc) = *(const short8*)(Vg + (size_t)r * 2048 + col);
  }

  f32x16 acc[2];  // acc[d]: ctx^T[dh = d*32 + rowmap][q = ln31]
#pragma unroll
  for (int d = 0; d < 2; d++) acc[d] = (f32x16)0.0f;
  float lrow = 0.0f;  // per-lane denom partial for q = ln31

  for (int t = 0; t < 32; t++) {
    const int buf = t & 1;
    __syncthreads();

    // prefetch next K/V tile into registers (in flight during QK^T)
    short8 kreg[2], vreg[2];
    const bool havenext = (t + 1) < 32;
    if (havenext) {
      int kt2 = (t + 1) * 64;
#pragma unroll
      for (int c = 0; c < 2; c++) {
        int e = (c * 256 + tid) * 8;
        int r = e >> 6, col = e & 63;
        kreg[c] = *(const short8*)(Kg + (size_t)(kt2 + r) * 64 + col);
        vreg[c] = *(const short8*)(Vg + (size_t)r * 2048 + kt2 + col);
      }
    }

    // Per k-half kb (32 keys): S^T = K*Q^T (4 mfma), exp2, pack, permlane.
    unsigned bw[2][2][4];
#pragma unroll
    for (int kb = 0; kb < 2; kb++) {
      f32x16 s = (f32x16)0.0f;
      __builtin_amdgcn_s_setprio(1);
#pragma unroll
      for (int m = 0; m < 4; m++) {
        const int krow = kb * 32 + ln31;
        short8 kf = *(const short8*)(Ks[buf] + krow * 64 + SWZ(m * 16 + hi * 8, krow));
        s = __builtin_amdgcn_mfma_f32_32x32x16_bf16(kf, qf[m], s, 0, 0, 0);
      }
      __builtin_amdgcn_s_setprio(0);
      // s[reg] is for k(in-tile) = kb*32 + 8*(reg>>2) + 4*hi + (reg&3)
      unsigned w[8];
#pragma unroll
      for (int g = 0; g < 4; g++) {
        int4 m4 = *(const int4*)(mg + t * 64 + kb * 32 + g * 8 + hi * 4);
        float mb0 = (m4.x == 0) ? -1.5e30f : 0.0f;
        float mb1 = (m4.y == 0) ? -1.5e30f : 0.0f;
        float mb2 = (m4.z == 0) ? -1.5e30f : 0.0f;
        float mb3 = (m4.w == 0) ? -1.5e30f : 0.0f;
        float p0 = exp2_fast(fmaf(s[4 * g + 0], C2, mb0));
        float p1 = exp2_fast(fmaf(s[4 * g + 1], C2, mb1));
        float p2 = exp2_fast(fmaf(s[4 * g + 2], C2, mb2));
        float p3 = exp2_fast(fmaf(s[4 * g + 3], C2, mb3));
        lrow += (p0 + p1) + (p2 + p3);
        w[2 * g]     = pack2(p0, p1);
        w[2 * g + 1] = pack2(p2, p3);
      }
      // permlane32_swap pairing w[g] with w[g+2] (+8 k) yields both halves (T12)
#pragma unroll
      for (int c = 0; c < 2; c++) {
        auto r0 = __builtin_amdgcn_permlane32_swap(w[c], w[2 + c], false, false);
        bw[kb][0][c]     = r0[0];
        bw[kb][0][2 + c] = r0[1];
        auto r1 = __builtin_amdgcn_permlane32_swap(w[4 + c], w[6 + c], false, false);
        bw[kb][1][c]     = r1[0];
        bw[kb][1][2 + c] = r1[1];
      }
    }

    // write prefetched tile to the other buffer (visible after next barrier)
    if (havenext) {
#pragma unroll
      for (int c = 0; c < 2; c++) {
        int e = (c * 256 + tid) * 8;
        int r = e >> 6, col = e & 63;
        int sc = SWZ(col, r);
        *(short8*)(Ks[buf ^ 1] + r * 64 + sc) = kreg[c];
        *(short8*)(Vs[buf ^ 1] + r * 64 + sc) = vreg[c];
      }
    }

    // ctx^T += V^T(64dh x 64k) * P^T(64k x 32q): 8 mfma_32x32x16
    __builtin_amdgcn_s_setprio(1);
#pragma unroll
    for (int d = 0; d < 2; d++) {
#pragma unroll
      for (int kb = 0; kb < 2; kb++) {
#pragma unroll
        for (int mp = 0; mp < 2; mp++) {
          const int vrow = d * 32 + ln31;
          short8 vf = *(const short8*)(Vs[buf] + vrow * 64 +
                                       SWZ(kb * 32 + mp * 16 + hi * 8, vrow));
          union { unsigned w4[4]; short8 s8; } u;
          u.w4[0] = bw[kb][mp][0]; u.w4[1] = bw[kb][mp][1];
          u.w4[2] = bw[kb][mp][2]; u.w4[3] = bw[kb][mp][3];
          acc[d] = __builtin_amdgcn_mfma_f32_32x32x16_bf16(vf, u.s8, acc[d], 0, 0, 0);
        }
      }
    }
    __builtin_amdgcn_s_setprio(0);
  }

  // epilogue: finish denom (lanes l, l^32 share q), scale, packed 8B stores.
  // acc[d][reg]: dh = d*32 + 8*(reg>>2) + 4*hi + (reg&3), q = ln31.
  float l = lrow + __shfl_xor(lrow, 32);
  float inv = 1.0f / l;
  const int s = q0 + qr0 + ln31;
  u16* base = Ct + ((size_t)(b * 2048 + s)) * 1024 + h * 64 + hi * 4;
#pragma unroll
  for (int d = 0; d < 2; d++) {
#pragma unroll
    for (int g = 0; g < 4; g++) {
      u16 o[4];
      o[0] = f2bf(acc[d][4 * g + 0] * inv);
      o[1] = f2bf(acc[d][4 * g + 1] * inv);
      o[2] = f2bf(acc[d][4 * g + 2] * inv);
      o[3] = f2bf(acc[d][4 * g + 3] * inv);
      *(short4v*)(base + d * 32 + g * 8) = *(const short4v*)o;
    }
  }
}

// ---------------- launch ----------------

extern "C" void kernel_launch(void* const* d_in, const int* in_sizes, int n_in,
                              void* d_out, int out_size, void* d_ws, size_t ws_size,
                              hipStream_t stream) {
  int iq, ik, iv, im, iWq, ibq, iWk, ibk, iWv, ibv, iWo, ibo;
  if (in_sizes[0] == 8388608) {  // dict order: query first
    iq = 0; ik = 1; iv = 2; im = 3;
    iWq = 4; ibq = 5; iWk = 6; ibk = 7; iWv = 8; ibv = 9; iWo = 10; ibo = 11;
  } else {                        // alphabetical fallback
    iWk = 0; iWo = 1; iWq = 2; iWv = 3;
    ibk = 4; ibo = 5; ibq = 6; ibv = 7;
    ik = 8; im = 9; iq = 10; iv = 11;
  }
  const float* query = (const float*)d_in[iq];
  const float* key   = (const float*)d_in[ik];
  const float* value = (const float*)d_in[iv];
  const int*   mask  = (const int*)d_in[im];
  const float* Wq = (const float*)d_in[iWq];
  const float* bq = (const float*)d_in[ibq];
  const float* Wk = (const float*)d_in[iWk];
  const float* bk = (const float*)d_in[ibk];
  const float* Wv = (const float*)d_in[iWv];
  const float* bv = (const float*)d_in[ibv];
  const float* Wo = (const float*)d_in[iWo];
  const float* bo = (const float*)d_in[ibo];

  const long U  = 8388608;   // 4*2048*1024
  const long Wn = 1048576;   // 1024*1024
  u16* ws = (u16*)d_ws;
  u16* cq   = ws;            // bf16 query          16.8 MB
  u16* ck   = cq + U;        // bf16 key            16.8 MB
  u16* cv   = ck + U;        // bf16 value          16.8 MB
  u16* cWq  = cv + U;        // bf16 weights         2.1 MB x4
  u16* cWk  = cWq + Wn;
  u16* cWv  = cWk + Wn;
  u16* cWo  = cWv + Wn;
  u16* qws  = cWo + Wn;      // Q (b,h,s,dh)        16.8 MB
  u16* kws  = qws + U;       // K (b,h,s,dh)        16.8 MB
  u16* cws  = ck;            // alias: ck dead once attn runs (post-GEMMs)

  // Batched QKV needs V's output distinct from cq (Q-proj reads cq
  // concurrently). Take a fresh region if the workspace allows; else fall
  // back to the validated sequential path with vtws aliasing cq.
  const size_t need_batched = (size_t)(7 * U + 4 * Wn) * sizeof(u16);  // 109 MB
  const bool batched = ws_size >= need_batched;
  u16* vtws = batched ? (kws + U) : cq;   // V^T (b,h,dh,s)  16.8 MB

  dim3 blk(256);

  CArgs ca;
  ca.in[0] = query; ca.out[0] = cq;  ca.n[0] = (int)U;
  ca.in[1] = key;   ca.out[1] = ck;  ca.n[1] = (int)U;
  ca.in[2] = value; ca.out[2] = cv;  ca.n[2] = (int)U;
  ca.in[3] = Wq;    ca.out[3] = cWq; ca.n[3] = (int)Wn;
  ca.in[4] = Wk;    ca.out[4] = cWk; ca.n[4] = (int)Wn;
  ca.in[5] = Wv;    ca.out[5] = cWv; ca.n[5] = (int)Wn;
  ca.in[6] = Wo;    ca.out[6] = cWo; ca.n[6] = (int)Wn;
  conv_bf16<<<dim3(4096, 7), blk, 0, stream>>>(ca);

  dim3 gproj(8, 64);  // N/128 x M/128
  if (batched) {
    G3 g3;
    g3.A[0] = cq; g3.W[0] = cWq; g3.bias[0] = bq; g3.C[0] = qws;  g3.mode[0] = 1;
    g3.A[1] = ck; g3.W[1] = cWk; g3.bias[1] = bk; g3.C[1] = kws;  g3.mode[1] = 1;
    g3.A[2] = cv; g3.W[2] = cWv; g3.bias[2] = bv; g3.C[2] = vtws; g3.mode[2] = 2;
    gemm_qkv<<<dim3(8, 64, 3), blk, 0, stream>>>(g3);
  } else {
    gemm_bt<false><<<gproj, blk, 0, stream>>>(cq, cWq, bq, qws, 8192, 1024, 1024, 1);
    gemm_bt<false><<<gproj, blk, 0, stream>>>(ck, cWk, bk, kws, 8192, 1024, 1024, 1);
    gemm_bt<false><<<gproj, blk, 0, stream>>>(cv, cWv, bv, vtws, 8192, 1024, 1024, 2);
  }
  attn<<<dim3(16, 64), blk, 0, stream>>>(qws, kws, vtws, mask, cws);
  gemm_bt<true><<<gproj, blk, 0, stream>>>(cws, cWo, bo, d_out, 8192, 1024, 1024, 0);
}

// Round 8
// 390.679 us; speedup vs baseline: 1.2564x; 1.0985x over previous
//
#include <hip/hip_runtime.h>
#include <hip/hip_bf16.h>

typedef unsigned short u16;
typedef __attribute__((ext_vector_type(4))) short short4v;
typedef __attribute__((ext_vector_type(8))) short short8;
typedef __attribute__((ext_vector_type(4))) float float4v;
typedef __attribute__((ext_vector_type(16))) float f32x16;

__device__ __forceinline__ void async_copy16(const void* g, void* l) {
  // HW-validated (r2 vs r3 bit-identity): 16B/lane global->LDS DMA
  __builtin_amdgcn_global_load_lds(
      (const __attribute__((address_space(1))) unsigned int*)g,
      (__attribute__((address_space(3))) unsigned int*)l,
      16, 0, 0);
}

__device__ __forceinline__ u16 f2bf(float f) {
  __hip_bfloat16 h = __float2bfloat16(f);  // RNE
  return *reinterpret_cast<u16*>(&h);
}

__device__ __forceinline__ unsigned pack2(float a, float b) {
  return (unsigned)f2bf(a) | ((unsigned)f2bf(b) << 16);
}

// native 2^x: v_exp_f32 computes 2^S0 (ISA). __exp2f doesn't exist in HIP.
__device__ __forceinline__ float exp2_fast(float x) {
  return __builtin_amdgcn_exp2f(x);
}

// ---------------- fp32 -> bf16 conversion pass ----------------
struct CArgs {
  const float* in[7];
  u16* out[7];
  int n[7];
};

__global__ void conv_bf16(CArgs a) {
  int t = blockIdx.y;
  int n = a.n[t];
  long i = ((long)blockIdx.x * blockDim.x + threadIdx.x) * 8;
  if (i >= n) return;
  const float4v* f = (const float4v*)(a.in[t] + i);
  float4v lo = f[0], hi = f[1];
  u16 o[8];
  o[0] = f2bf(lo.x); o[1] = f2bf(lo.y); o[2] = f2bf(lo.z); o[3] = f2bf(lo.w);
  o[4] = f2bf(hi.x); o[5] = f2bf(hi.y); o[6] = f2bf(hi.z); o[7] = f2bf(hi.w);
  *(short8*)(a.out[t] + i) = *(const short8*)o;
}

// ---------------- GEMM (m97 single-buffer + T1 XCD swizzle) -----------------
// r6/r7 validated stack + NEW: XCD-chunked blockIdx swizzle. gridDim=(8,64):
// the 8 blocks sharing an A-row-panel are consecutive linear bids, which the
// dispatcher round-robins onto 8 DIFFERENT XCDs -> each panel fetched into 8
// L2s (134MB panel traffic/GEMM). Chunked remap (bijective for nwg%8==0)
// gives each XCD a contiguous 64-block range = 8 panels x 8 col-tiles ->
// each panel fetched ONCE per XCD-L2 and reused by 8 blocks (~17MB).
// A,W bf16 [.,K] row-major; bias fp32. mode 0: fp32 C[m*N+n];
// mode 1: bf16 (b,h,s,dh); mode 2: bf16 (b,h,dh,s) transposed
template <bool OUT_F32>
__device__ __forceinline__
void gemm_body(const u16* __restrict__ A, const u16* __restrict__ W,
               const float* __restrict__ bias, void* __restrict__ Cp,
               int M, int N, int K, int mode) {
  __shared__ __attribute__((aligned(16))) u16 As[128 * 32];
  __shared__ __attribute__((aligned(16))) u16 Ws[128 * 32];

  const int tid  = threadIdx.x;
  const int lane = tid & 63;
  const int wave = tid >> 6;
  const int ln15 = lane & 15;
  const int quad = lane >> 4;

  // T1 XCD-chunked swizzle (speed-only; bijective when nwg%8==0)
  int bx = blockIdx.x, by = blockIdx.y;
  {
    const int nwg = gridDim.x * gridDim.y;
    if (gridDim.x == 8 && (nwg & 7) == 0) {
      const int per = nwg >> 3;
      const int bid = by * 8 + bx;
      const int nlin = (bid & 7) * per + (bid >> 3);
      bx = nlin & 7;
      by = nlin >> 3;
    }
  }
  const int m0 = by * 128;
  const int n0 = bx * 128;
  const int wm = (wave & 1) * 64;
  const int wn = (wave >> 1) * 64;

  float4v acc[4][4];
#pragma unroll
  for (int i = 0; i < 4; i++)
#pragma unroll
    for (int j = 0; j < 4; j++) acc[i][j] = (float4v)0.0f;

  for (int k0 = 0; k0 < K; k0 += 32) {
#pragma unroll
    for (int c = 0; c < 2; c++) {
      int e = (c * 256 + tid) * 8;
      int r = e >> 5, col = e & 31;
      async_copy16(A + (size_t)(m0 + r) * K + k0 + col, (void*)(As + e));
      async_copy16(W + (size_t)(n0 + r) * K + k0 + col, (void*)(Ws + e));
    }
    __syncthreads();

    short8 af[4], bfr[4];
#pragma unroll
    for (int i = 0; i < 4; i++)
      af[i] = *(const short8*)(As + (wm + i * 16 + ln15) * 32 + quad * 8);
#pragma unroll
    for (int j = 0; j < 4; j++)
      bfr[j] = *(const short8*)(Ws + (wn + j * 16 + ln15) * 32 + quad * 8);
#pragma unroll
    for (int i = 0; i < 4; i++)
#pragma unroll
      for (int j = 0; j < 4; j++)
        acc[i][j] = __builtin_amdgcn_mfma_f32_16x16x32_bf16(af[i], bfr[j], acc[i][j], 0, 0, 0);
    __syncthreads();
  }

  // epilogue; C/D layout: col = lane&15, row = quad*4 + reg (HW-verified)
#pragma unroll
  for (int j = 0; j < 4; j++) {
    int n = n0 + wn + j * 16 + ln15;
    float bval = bias[n];
#pragma unroll
    for (int i = 0; i < 4; i++) {
#pragma unroll
      for (int r = 0; r < 4; r++) {
        int m = m0 + wm + i * 16 + quad * 4 + r;
        float v = acc[i][j][r] + bval;
        size_t addr;
        if (mode == 0) {
          addr = (size_t)m * N + n;
        } else {
          int b = m >> 11, s = m & 2047;
          int h = n >> 6, dh = n & 63;
          if (mode == 1) addr = (((size_t)(b * 16 + h)) * 2048 + s) * 64 + dh;
          else           addr = (((size_t)(b * 16 + h)) * 64 + dh) * 2048 + s;
        }
        if (OUT_F32) ((float*)Cp)[addr] = v;
        else         ((u16*)Cp)[addr] = f2bf(v);
      }
    }
  }
}

template <bool OUT_F32>
__global__ __launch_bounds__(256, 3)
void gemm_bt(const u16* __restrict__ A, const u16* __restrict__ W,
             const float* __restrict__ bias, void* __restrict__ Cp,
             int M, int N, int K, int mode) {
  gemm_body<OUT_F32>(A, W, bias, Cp, M, N, K, mode);
}

// z-batched Q/K/V projections: one launch, 1536 blocks, no inter-launch gaps.
struct G3 {
  const u16* A[3]; const u16* W[3]; const float* bias[3];
  void* C[3]; int mode[3];
};

__global__ __launch_bounds__(256, 3)
void gemm_qkv(G3 g) {
  const int z = blockIdx.z;
  gemm_body<false>(g.A[z], g.W[z], g.bias[z], g.C[z], 8192, 1024, 1024, g.mode[z]);
}

// ---------------- Flash attention (32x32 MFMA, T12, gload_lds staging) -----
// r5/r7 structure (141us, VGPR 64, no spill) + NEW: K/V staged by
// global_load_lds with PRE-SWIZZLED SOURCE (rule 21: linear LDS dest +
// inverse-swizzled global col + swizzled read; SWZ is an involution and
// permutes whole 16B chunks, so per-lane source swizzle is exact).
// Removes kreg/vreg (16 VGPR), 4 ds_write_b128 and half the staging
// address calc per tile; loads stay in flight across the whole compute
// phase and the next barrier's vmcnt(0) lands them.
//
// S^T = mfma_32x32x16(K, Q): D col = q = lane&31 (fixed per lane!),
// row = k = (reg&3) + 8*(reg>>2) + 4*(lane>>5)  [m74/m101 HW-verified].
// P->B repack: 16 cvt_pk words + 8 permlane32_swap per KV-64 tile (T12).
// Softmax: p = exp2(fma(s, log2e/32, mb)).
// r6 lesson: do NOT add acc ILP splits -- VGPR headroom beats MFMA ILP here.
#define SWZ(c, r) ((c) ^ (((r) & 7) << 3))
__global__ __launch_bounds__(256, 4)
void attn(const u16* __restrict__ Q, const u16* __restrict__ K,
          const u16* __restrict__ Vt, const int* __restrict__ mask,
          u16* __restrict__ Ct) {
  __shared__ __attribute__((aligned(16))) u16 Ks[2][64 * 64];
  __shared__ __attribute__((aligned(16))) u16 Vs[2][64 * 64];

  const int tid  = threadIdx.x;
  const int lane = tid & 63;
  const int wave = tid >> 6;
  const int ln31 = lane & 31;
  const int hi   = lane >> 5;
  const int bh = blockIdx.y;
  const int b = bh >> 4, h = bh & 15;
  const int q0 = blockIdx.x * 128;
  const int qr0 = wave * 32;

  const u16* Qg = Q + ((size_t)bh * 2048 + q0 + qr0) * 64;
  const u16* Kg = K + (size_t)bh * 2048 * 64;
  const u16* Vg = Vt + (size_t)bh * 64 * 2048;
  const int* mg = mask + b * 2048;

  const float C2 = 0.04508422f;  // log2(e)/32

  // per-thread staging geometry (shared by all tiles): e linear in tid
  // (matches gload_lds's lane-linear LDS write); source col pre-swizzled.
  // e covers 64 rows x 64 cols in 16B chunks, each exactly once.

  // hoist Q fragments: qf[m] = Q[q = ln31][dh = m*16 + hi*8 .. +8]
  short8 qf[4];
#pragma unroll
  for (int m = 0; m < 4; m++)
    qf[m] = *(const short8*)(Qg + (size_t)ln31 * 64 + m * 16 + hi * 8);

  // stage K/V tile 0 into buf 0: direct-to-LDS, pre-swizzled source
#pragma unroll
  for (int c = 0; c < 2; c++) {
    int e = (c * 256 + tid) * 8;
    int r = e >> 6, col = e & 63;
    int scol = SWZ(col, r);
    async_copy16(Kg + (size_t)r * 64 + scol, (void*)(Ks[0] + e));
    async_copy16(Vg + (size_t)r * 2048 + scol, (void*)(Vs[0] + e));
  }

  f32x16 acc[2];  // acc[d]: ctx^T[dh = d*32 + rowmap][q = ln31]
#pragma unroll
  for (int d = 0; d < 2; d++) acc[d] = (f32x16)0.0f;
  float lrow = 0.0f;  // per-lane denom partial for q = ln31

  for (int t = 0; t < 32; t++) {
    const int buf = t & 1;
    __syncthreads();  // drains vmcnt(0): buf's staged tile is now resident

    // prefetch next K/V tile: fire-and-forget direct-to-LDS into buf^1;
    // stays in flight under the whole QK/softmax/PV phase.
    if ((t + 1) < 32) {
      const int kt2 = (t + 1) * 64;
#pragma unroll
      for (int c = 0; c < 2; c++) {
        int e = (c * 256 + tid) * 8;
        int r = e >> 6, col = e & 63;
        int scol = SWZ(col, r);
        async_copy16(Kg + (size_t)(kt2 + r) * 64 + scol, (void*)(Ks[buf ^ 1] + e));
        async_copy16(Vg + (size_t)r * 2048 + kt2 + scol, (void*)(Vs[buf ^ 1] + e));
      }
    }

    // Per k-half kb (32 keys): S^T = K*Q^T (4 mfma), exp2, pack, permlane.
    unsigned bw[2][2][4];
#pragma unroll
    for (int kb = 0; kb < 2; kb++) {
      f32x16 s = (f32x16)0.0f;
      __builtin_amdgcn_s_setprio(1);
#pragma unroll
      for (int m = 0; m < 4; m++) {
        const int krow = kb * 32 + ln31;
        short8 kf = *(const short8*)(Ks[buf] + krow * 64 + SWZ(m * 16 + hi * 8, krow));
        s = __builtin_amdgcn_mfma_f32_32x32x16_bf16(kf, qf[m], s, 0, 0, 0);
      }
      __builtin_amdgcn_s_setprio(0);
      // s[reg] is for k(in-tile) = kb*32 + 8*(reg>>2) + 4*hi + (reg&3)
      unsigned w[8];
#pragma unroll
      for (int g = 0; g < 4; g++) {
        int4 m4 = *(const int4*)(mg + t * 64 + kb * 32 + g * 8 + hi * 4);
        float mb0 = (m4.x == 0) ? -1.5e30f : 0.0f;
        float mb1 = (m4.y == 0) ? -1.5e30f : 0.0f;
        float mb2 = (m4.z == 0) ? -1.5e30f : 0.0f;
        float mb3 = (m4.w == 0) ? -1.5e30f : 0.0f;
        float p0 = exp2_fast(fmaf(s[4 * g + 0], C2, mb0));
        float p1 = exp2_fast(fmaf(s[4 * g + 1], C2, mb1));
        float p2 = exp2_fast(fmaf(s[4 * g + 2], C2, mb2));
        float p3 = exp2_fast(fmaf(s[4 * g + 3], C2, mb3));
        lrow += (p0 + p1) + (p2 + p3);
        w[2 * g]     = pack2(p0, p1);
        w[2 * g + 1] = pack2(p2, p3);
      }
      // permlane32_swap pairing w[g] with w[g+2] (+8 k) yields both halves (T12)
#pragma unroll
      for (int c = 0; c < 2; c++) {
        auto r0 = __builtin_amdgcn_permlane32_swap(w[c], w[2 + c], false, false);
        bw[kb][0][c]     = r0[0];
        bw[kb][0][2 + c] = r0[1];
        auto r1 = __builtin_amdgcn_permlane32_swap(w[4 + c], w[6 + c], false, false);
        bw[kb][1][c]     = r1[0];
        bw[kb][1][2 + c] = r1[1];
      }
    }

    // ctx^T += V^T(64dh x 64k) * P^T(64k x 32q): 8 mfma_32x32x16
    __builtin_amdgcn_s_setprio(1);
#pragma unroll
    for (int d = 0; d < 2; d++) {
#pragma unroll
      for (int kb = 0; kb < 2; kb++) {
#pragma unroll
        for (int mp = 0; mp < 2; mp++) {
          const int vrow = d * 32 + ln31;
          short8 vf = *(const short8*)(Vs[buf] + vrow * 64 +
                                       SWZ(kb * 32 + mp * 16 + hi * 8, vrow));
          union { unsigned w4[4]; short8 s8; } u;
          u.w4[0] = bw[kb][mp][0]; u.w4[1] = bw[kb][mp][1];
          u.w4[2] = bw[kb][mp][2]; u.w4[3] = bw[kb][mp][3];
          acc[d] = __builtin_amdgcn_mfma_f32_32x32x16_bf16(vf, u.s8, acc[d], 0, 0, 0);
        }
      }
    }
    __builtin_amdgcn_s_setprio(0);
  }

  // epilogue: finish denom (lanes l, l^32 share q), scale, packed 8B stores.
  // acc[d][reg]: dh = d*32 + 8*(reg>>2) + 4*hi + (reg&3), q = ln31.
  float l = lrow + __shfl_xor(lrow, 32);
  float inv = 1.0f / l;
  const int s = q0 + qr0 + ln31;
  u16* base = Ct + ((size_t)(b * 2048 + s)) * 1024 + h * 64 + hi * 4;
#pragma unroll
  for (int d = 0; d < 2; d++) {
#pragma unroll
    for (int g = 0; g < 4; g++) {
      u16 o[4];
      o[0] = f2bf(acc[d][4 * g + 0] * inv);
      o[1] = f2bf(acc[d][4 * g + 1] * inv);
      o[2] = f2bf(acc[d][4 * g + 2] * inv);
      o[3] = f2bf(acc[d][4 * g + 3] * inv);
      *(short4v*)(base + d * 32 + g * 8) = *(const short4v*)o;
    }
  }
}

// ---------------- launch ----------------

extern "C" void kernel_launch(void* const* d_in, const int* in_sizes, int n_in,
                              void* d_out, int out_size, void* d_ws, size_t ws_size,
                              hipStream_t stream) {
  int iq, ik, iv, im, iWq, ibq, iWk, ibk, iWv, ibv, iWo, ibo;
  if (in_sizes[0] == 8388608) {  // dict order: query first
    iq = 0; ik = 1; iv = 2; im = 3;
    iWq = 4; ibq = 5; iWk = 6; ibk = 7; iWv = 8; ibv = 9; iWo = 10; ibo = 11;
  } else {                        // alphabetical fallback
    iWk = 0; iWo = 1; iWq = 2; iWv = 3;
    ibk = 4; ibo = 5; ibq = 6; ibv = 7;
    ik = 8; im = 9; iq = 10; iv = 11;
  }
  const float* query = (const float*)d_in[iq];
  const float* key   = (const float*)d_in[ik];
  const float* value = (const float*)d_in[iv];
  const int*   mask  = (const int*)d_in[im];
  const float* Wq = (const float*)d_in[iWq];
  const float* bq = (const float*)d_in[ibq];
  const float* Wk = (const float*)d_in[iWk];
  const float* bk = (const float*)d_in[ibk];
  const float* Wv = (const float*)d_in[iWv];
  const float* bv = (const float*)d_in[ibv];
  const float* Wo = (const float*)d_in[iWo];
  const float* bo = (const float*)d_in[ibo];

  const long U  = 8388608;   // 4*2048*1024
  const long Wn = 1048576;   // 1024*1024
  u16* ws = (u16*)d_ws;
  u16* cq   = ws;            // bf16 query          16.8 MB
  u16* ck   = cq + U;        // bf16 key            16.8 MB
  u16* cv   = ck + U;        // bf16 value          16.8 MB
  u16* cWq  = cv + U;        // bf16 weights         2.1 MB x4
  u16* cWk  = cWq + Wn;
  u16* cWv  = cWk + Wn;
  u16* cWo  = cWv + Wn;
  u16* qws  = cWo + Wn;      // Q (b,h,s,dh)        16.8 MB
  u16* kws  = qws + U;       // K (b,h,s,dh)        16.8 MB
  u16* cws  = ck;            // alias: ck dead once attn runs (post-GEMMs)

  // Batched QKV needs V's output distinct from cq (Q-proj reads cq
  // concurrently). Take a fresh region if the workspace allows; else fall
  // back to the validated sequential path with vtws aliasing cq.
  const size_t need_batched = (size_t)(7 * U + 4 * Wn) * sizeof(u16);  // 109 MB
  const bool batched = ws_size >= need_batched;
  u16* vtws = batched ? (kws + U) : cq;   // V^T (b,h,dh,s)  16.8 MB

  dim3 blk(256);

  CArgs ca;
  ca.in[0] = query; ca.out[0] = cq;  ca.n[0] = (int)U;
  ca.in[1] = key;   ca.out[1] = ck;  ca.n[1] = (int)U;
  ca.in[2] = value; ca.out[2] = cv;  ca.n[2] = (int)U;
  ca.in[3] = Wq;    ca.out[3] = cWq; ca.n[3] = (int)Wn;
  ca.in[4] = Wk;    ca.out[4] = cWk; ca.n[4] = (int)Wn;
  ca.in[5] = Wv;    ca.out[5] = cWv; ca.n[5] = (int)Wn;
  ca.in[6] = Wo;    ca.out[6] = cWo; ca.n[6] = (int)Wn;
  conv_bf16<<<dim3(4096, 7), blk, 0, stream>>>(ca);

  dim3 gproj(8, 64);  // N/128 x M/128
  if (batched) {
    G3 g3;
    g3.A[0] = cq; g3.W[0] = cWq; g3.bias[0] = bq; g3.C[0] = qws;  g3.mode[0] = 1;
    g3.A[1] = ck; g3.W[1] = cWk; g3.bias[1] = bk; g3.C[1] = kws;  g3.mode[1] = 1;
    g3.A[2] = cv; g3.W[2] = cWv; g3.bias[2] = bv; g3.C[2] = vtws; g3.mode[2] = 2;
    gemm_qkv<<<dim3(8, 64, 3), blk, 0, stream>>>(g3);
  } else {
    gemm_bt<false><<<gproj, blk, 0, stream>>>(cq, cWq, bq, qws, 8192, 1024, 1024, 1);
    gemm_bt<false><<<gproj, blk, 0, stream>>>(ck, cWk, bk, kws, 8192, 1024, 1024, 1);
    gemm_bt<false><<<gproj, blk, 0, stream>>>(cv, cWv, bv, vtws, 8192, 1024, 1024, 2);
  }
  attn<<<dim3(16, 64), blk, 0, stream>>>(qws, kws, vtws, mask, cws);
  gemm_bt<true><<<gproj, blk, 0, stream>>>(cws, cWo, bo, d_out, 8192, 1024, 1024, 0);
}

// Round 9
// 360.888 us; speedup vs baseline: 1.3602x; 1.0825x over previous
//
#include <hip/hip_runtime.h>
#include <hip/hip_bf16.h>

typedef unsigned short u16;
typedef __attribute__((ext_vector_type(4))) short short4v;
typedef __attribute__((ext_vector_type(8))) short short8;
typedef __attribute__((ext_vector_type(4))) float float4v;
typedef __attribute__((ext_vector_type(16))) float f32x16;

// XOR swizzle: permutes 16B chunks within a 128B row-group, involution.
// Validated bit-exact with global_load_lds pre-swizzled source (r8).
#define SWZ(c, r) ((c) ^ (((r) & 7) << 3))

__device__ __forceinline__ void async_copy16(const void* g, void* l) {
  // HW-validated (r2 vs r3 bit-identity): 16B/lane global->LDS DMA
  __builtin_amdgcn_global_load_lds(
      (const __attribute__((address_space(1))) unsigned int*)g,
      (__attribute__((address_space(3))) unsigned int*)l,
      16, 0, 0);
}

__device__ __forceinline__ u16 f2bf(float f) {
  __hip_bfloat16 h = __float2bfloat16(f);  // RNE
  return *reinterpret_cast<u16*>(&h);
}

__device__ __forceinline__ unsigned pack2(float a, float b) {
  return (unsigned)f2bf(a) | ((unsigned)f2bf(b) << 16);
}

// native 2^x: v_exp_f32 computes 2^S0 (ISA). __exp2f doesn't exist in HIP.
__device__ __forceinline__ float exp2_fast(float x) {
  return __builtin_amdgcn_exp2f(x);
}

// ---------------- fp32 -> bf16 conversion pass ----------------
struct CArgs {
  const float* in[7];
  u16* out[7];
  int n[7];
};

__global__ void conv_bf16(CArgs a) {
  int t = blockIdx.y;
  int n = a.n[t];
  long i = ((long)blockIdx.x * blockDim.x + threadIdx.x) * 8;
  if (i >= n) return;
  const float4v* f = (const float4v*)(a.in[t] + i);
  float4v lo = f[0], hi = f[1];
  u16 o[8];
  o[0] = f2bf(lo.x); o[1] = f2bf(lo.y); o[2] = f2bf(lo.z); o[3] = f2bf(lo.w);
  o[4] = f2bf(hi.x); o[5] = f2bf(hi.y); o[6] = f2bf(hi.z); o[7] = f2bf(hi.w);
  *(short8*)(a.out[t] + i) = *(const short8*)o;
}

// ---------------- GEMM (BK=64 + T1 XCD swizzle + LDS swizzle) ---------------
// r8 stack + NEW: BK=64 (16 K-steps instead of 32 -> HALF the barrier/
// vmcnt(0)-drain overhead, the documented ~20% m97 stall). LDS 32KB
// single-buffered: at (256,3) LDS allows 5 blocks/CU, VGPR caps 3 ->
// occupancy unchanged vs BK=32 (m132's BK=128 failure was the 64KB->
// 2 blocks cliff, avoided here). Frag reads at 128B row stride would be
// 16-way bank conflicts -> same SWZ + pre-swizzled gload_lds source as
// attn r8 (bit-exact validated) keeps them 2-way (free).
// NEW: oscale epilogue factor (folds attention 1/32*log2e into Q-proj).
// A,W bf16 [.,K] row-major; bias fp32. mode 0: fp32 C[m*N+n];
// mode 1: bf16 (b,h,s,dh); mode 2: bf16 (b,h,dh,s) transposed
template <bool OUT_F32>
__device__ __forceinline__
void gemm_body(const u16* __restrict__ A, const u16* __restrict__ W,
               const float* __restrict__ bias, void* __restrict__ Cp,
               int M, int N, int K, int mode, float oscale) {
  __shared__ __attribute__((aligned(16))) u16 As[128 * 64];
  __shared__ __attribute__((aligned(16))) u16 Ws[128 * 64];

  const int tid  = threadIdx.x;
  const int lane = tid & 63;
  const int wave = tid >> 6;
  const int ln15 = lane & 15;
  const int quad = lane >> 4;

  // T1 XCD-chunked swizzle (speed-only; bijective when nwg%8==0)
  int bx = blockIdx.x, by = blockIdx.y;
  {
    const int nwg = gridDim.x * gridDim.y;
    if (gridDim.x == 8 && (nwg & 7) == 0) {
      const int per = nwg >> 3;
      const int bid = by * 8 + bx;
      const int nlin = (bid & 7) * per + (bid >> 3);
      bx = nlin & 7;
      by = nlin >> 3;
    }
  }
  const int m0 = by * 128;
  const int n0 = bx * 128;
  const int wm = (wave & 1) * 64;
  const int wn = (wave >> 1) * 64;

  float4v acc[4][4];
#pragma unroll
  for (int i = 0; i < 4; i++)
#pragma unroll
    for (int j = 0; j < 4; j++) acc[i][j] = (float4v)0.0f;

  for (int k0 = 0; k0 < K; k0 += 64) {
#pragma unroll
    for (int c = 0; c < 4; c++) {
      int e = (c * 256 + tid) * 8;
      int r = e >> 6, col = e & 63;
      int scol = SWZ(col, r);   // LDS dest linear, source pre-swizzled
      async_copy16(A + (size_t)(m0 + r) * K + k0 + scol, (void*)(As + e));
      async_copy16(W + (size_t)(n0 + r) * K + k0 + scol, (void*)(Ws + e));
    }
    __syncthreads();

#pragma unroll
    for (int kk = 0; kk < 64; kk += 32) {
      short8 af[4], bfr[4];
#pragma unroll
      for (int i = 0; i < 4; i++) {
        const int row = wm + i * 16 + ln15;
        af[i] = *(const short8*)(As + row * 64 + SWZ(kk + quad * 8, row));
      }
#pragma unroll
      for (int j = 0; j < 4; j++) {
        const int row = wn + j * 16 + ln15;
        bfr[j] = *(const short8*)(Ws + row * 64 + SWZ(kk + quad * 8, row));
      }
#pragma unroll
      for (int i = 0; i < 4; i++)
#pragma unroll
        for (int j = 0; j < 4; j++)
          acc[i][j] = __builtin_amdgcn_mfma_f32_16x16x32_bf16(af[i], bfr[j], acc[i][j], 0, 0, 0);
    }
    __syncthreads();
  }

  // epilogue; C/D layout: col = lane&15, row = quad*4 + reg (HW-verified)
#pragma unroll
  for (int j = 0; j < 4; j++) {
    int n = n0 + wn + j * 16 + ln15;
    float bval = bias[n];
#pragma unroll
    for (int i = 0; i < 4; i++) {
#pragma unroll
      for (int r = 0; r < 4; r++) {
        int m = m0 + wm + i * 16 + quad * 4 + r;
        float v = (acc[i][j][r] + bval) * oscale;
        size_t addr;
        if (mode == 0) {
          addr = (size_t)m * N + n;
        } else {
          int b = m >> 11, s = m & 2047;
          int h = n >> 6, dh = n & 63;
          if (mode == 1) addr = (((size_t)(b * 16 + h)) * 2048 + s) * 64 + dh;
          else           addr = (((size_t)(b * 16 + h)) * 64 + dh) * 2048 + s;
        }
        if (OUT_F32) ((float*)Cp)[addr] = v;
        else         ((u16*)Cp)[addr] = f2bf(v);
      }
    }
  }
}

template <bool OUT_F32>
__global__ __launch_bounds__(256, 3)
void gemm_bt(const u16* __restrict__ A, const u16* __restrict__ W,
             const float* __restrict__ bias, void* __restrict__ Cp,
             int M, int N, int K, int mode, float oscale) {
  gemm_body<OUT_F32>(A, W, bias, Cp, M, N, K, mode, oscale);
}

// z-batched Q/K/V projections: one launch, 1536 blocks, no inter-launch gaps.
struct G3 {
  const u16* A[3]; const u16* W[3]; const float* bias[3];
  void* C[3]; int mode[3]; float oscale[3];
};

__global__ __launch_bounds__(256, 3)
void gemm_qkv(G3 g) {
  const int z = blockIdx.z;
  gemm_body<false>(g.A[z], g.W[z], g.bias[z], g.C[z], 8192, 1024, 1024,
                   g.mode[z], g.oscale[z]);
}

// ---------------- Flash attention (32x32 MFMA, T12, gload_lds staging) -----
// r8 structure (127us, VGPR 60) + NEW: (a) score scale folded into Q-proj
// epilogue (Q already carries log2e/32 -> p = exp2(s), no per-element fma);
// (b) mask ballot fast-path: 1 load + __ballot per tile; all-unmasked
// (the actual benchmark mask) skips 8 int4 loads + 32 cndmask per tile.
// Slow path (any masked key) keeps the exact int4+bias code, s + mb.
//
// S^T = mfma_32x32x16(K, Q): D col = q = lane&31 (fixed per lane!),
// row = k = (reg&3) + 8*(reg>>2) + 4*(lane>>5)  [m74/m101 HW-verified].
// P->B repack: 16 cvt_pk words + 8 permlane32_swap per KV-64 tile (T12).
// Bank-conflict note: the 2^23 SQ_LDS_BANK_CONFLICT is the structural
// 8-words/bank floor of wave64 b128 reads -- not fixable, not debt.
// r6 lesson: do NOT add acc ILP splits -- VGPR headroom beats MFMA ILP here.
__global__ __launch_bounds__(256, 4)
void attn(const u16* __restrict__ Q, const u16* __restrict__ K,
          const u16* __restrict__ Vt, const int* __restrict__ mask,
          u16* __restrict__ Ct) {
  __shared__ __attribute__((aligned(16))) u16 Ks[2][64 * 64];
  __shared__ __attribute__((aligned(16))) u16 Vs[2][64 * 64];

  const int tid  = threadIdx.x;
  const int lane = tid & 63;
  const int wave = tid >> 6;
  const int ln31 = lane & 31;
  const int hi   = lane >> 5;
  const int bh = blockIdx.y;
  const int b = bh >> 4, h = bh & 15;
  const int q0 = blockIdx.x * 128;
  const int qr0 = wave * 32;

  const u16* Qg = Q + ((size_t)bh * 2048 + q0 + qr0) * 64;
  const u16* Kg = K + (size_t)bh * 2048 * 64;
  const u16* Vg = Vt + (size_t)bh * 64 * 2048;
  const int* mg = mask + b * 2048;

  // hoist Q fragments: qf[m] = Q[q = ln31][dh = m*16 + hi*8 .. +8]
  short8 qf[4];
#pragma unroll
  for (int m = 0; m < 4; m++)
    qf[m] = *(const short8*)(Qg + (size_t)ln31 * 64 + m * 16 + hi * 8);

  // stage K/V tile 0 into buf 0: direct-to-LDS, pre-swizzled source
#pragma unroll
  for (int c = 0; c < 2; c++) {
    int e = (c * 256 + tid) * 8;
    int r = e >> 6, col = e & 63;
    int scol = SWZ(col, r);
    async_copy16(Kg + (size_t)r * 64 + scol, (void*)(Ks[0] + e));
    async_copy16(Vg + (size_t)r * 2048 + scol, (void*)(Vs[0] + e));
  }

  f32x16 acc[2];  // acc[d]: ctx^T[dh = d*32 + rowmap][q = ln31]
#pragma unroll
  for (int d = 0; d < 2; d++) acc[d] = (f32x16)0.0f;
  float lrow = 0.0f;  // per-lane denom partial for q = ln31

  for (int t = 0; t < 32; t++) {
    const int buf = t & 1;
    __syncthreads();  // drains vmcnt(0): buf's staged tile is now resident

    // prefetch next K/V tile: fire-and-forget direct-to-LDS into buf^1;
    // stays in flight under the whole QK/softmax/PV phase.
    if ((t + 1) < 32) {
      const int kt2 = (t + 1) * 64;
#pragma unroll
      for (int c = 0; c < 2; c++) {
        int e = (c * 256 + tid) * 8;
        int r = e >> 6, col = e & 63;
        int scol = SWZ(col, r);
        async_copy16(Kg + (size_t)(kt2 + r) * 64 + scol, (void*)(Ks[buf ^ 1] + e));
        async_copy16(Vg + (size_t)r * 2048 + kt2 + scol, (void*)(Vs[buf ^ 1] + e));
      }
    }

    // mask fast-path: one bit per key, wave-uniform branch
    const int mv = mg[t * 64 + lane];
    const bool allone = (__ballot(mv != 0) == ~0ull);

    // Per k-half kb (32 keys): S^T = K*Q^T (4 mfma), exp2, pack, permlane.
    unsigned bw[2][2][4];
#pragma unroll
    for (int kb = 0; kb < 2; kb++) {
      f32x16 s = (f32x16)0.0f;
      __builtin_amdgcn_s_setprio(1);
#pragma unroll
      for (int m = 0; m < 4; m++) {
        const int krow = kb * 32 + ln31;
        short8 kf = *(const short8*)(Ks[buf] + krow * 64 + SWZ(m * 16 + hi * 8, krow));
        s = __builtin_amdgcn_mfma_f32_32x32x16_bf16(kf, qf[m], s, 0, 0, 0);
      }
      __builtin_amdgcn_s_setprio(0);
      // s[reg] is for k(in-tile) = kb*32 + 8*(reg>>2) + 4*hi + (reg&3)
      // Q carries log2e/32 (folded in projection) -> p = exp2(s [+ mb])
      unsigned w[8];
      if (allone) {
#pragma unroll
        for (int g = 0; g < 4; g++) {
          float p0 = exp2_fast(s[4 * g + 0]);
          float p1 = exp2_fast(s[4 * g + 1]);
          float p2 = exp2_fast(s[4 * g + 2]);
          float p3 = exp2_fast(s[4 * g + 3]);
          lrow += (p0 + p1) + (p2 + p3);
          w[2 * g]     = pack2(p0, p1);
          w[2 * g + 1] = pack2(p2, p3);
        }
      } else {
#pragma unroll
        for (int g = 0; g < 4; g++) {
          int4 m4 = *(const int4*)(mg + t * 64 + kb * 32 + g * 8 + hi * 4);
          float mb0 = (m4.x == 0) ? -1.5e30f : 0.0f;
          float mb1 = (m4.y == 0) ? -1.5e30f : 0.0f;
          float mb2 = (m4.z == 0) ? -1.5e30f : 0.0f;
          float mb3 = (m4.w == 0) ? -1.5e30f : 0.0f;
          float p0 = exp2_fast(s[4 * g + 0] + mb0);
          float p1 = exp2_fast(s[4 * g + 1] + mb1);
          float p2 = exp2_fast(s[4 * g + 2] + mb2);
          float p3 = exp2_fast(s[4 * g + 3] + mb3);
          lrow += (p0 + p1) + (p2 + p3);
          w[2 * g]     = pack2(p0, p1);
          w[2 * g + 1] = pack2(p2, p3);
        }
      }
      // permlane32_swap pairing w[g] with w[g+2] (+8 k) yields both halves (T12)
#pragma unroll
      for (int c = 0; c < 2; c++) {
        auto r0 = __builtin_amdgcn_permlane32_swap(w[c], w[2 + c], false, false);
        bw[kb][0][c]     = r0[0];
        bw[kb][0][2 + c] = r0[1];
        auto r1 = __builtin_amdgcn_permlane32_swap(w[4 + c], w[6 + c], false, false);
        bw[kb][1][c]     = r1[0];
        bw[kb][1][2 + c] = r1[1];
      }
    }

    // ctx^T += V^T(64dh x 64k) * P^T(64k x 32q): 8 mfma_32x32x16
    __builtin_amdgcn_s_setprio(1);
#pragma unroll
    for (int d = 0; d < 2; d++) {
#pragma unroll
      for (int kb = 0; kb < 2; kb++) {
#pragma unroll
        for (int mp = 0; mp < 2; mp++) {
          const int vrow = d * 32 + ln31;
          short8 vf = *(const short8*)(Vs[buf] + vrow * 64 +
                                       SWZ(kb * 32 + mp * 16 + hi * 8, vrow));
          union { unsigned w4[4]; short8 s8; } u;
          u.w4[0] = bw[kb][mp][0]; u.w4[1] = bw[kb][mp][1];
          u.w4[2] = bw[kb][mp][2]; u.w4[3] = bw[kb][mp][3];
          acc[d] = __builtin_amdgcn_mfma_f32_32x32x16_bf16(vf, u.s8, acc[d], 0, 0, 0);
        }
      }
    }
    __builtin_amdgcn_s_setprio(0);
  }

  // epilogue: finish denom (lanes l, l^32 share q), scale, packed 8B stores.
  // acc[d][reg]: dh = d*32 + 8*(reg>>2) + 4*hi + (reg&3), q = ln31.
  float l = lrow + __shfl_xor(lrow, 32);
  float inv = 1.0f / l;
  const int s = q0 + qr0 + ln31;
  u16* base = Ct + ((size_t)(b * 2048 + s)) * 1024 + h * 64 + hi * 4;
#pragma unroll
  for (int d = 0; d < 2; d++) {
#pragma unroll
    for (int g = 0; g < 4; g++) {
      u16 o[4];
      o[0] = f2bf(acc[d][4 * g + 0] * inv);
      o[1] = f2bf(acc[d][4 * g + 1] * inv);
      o[2] = f2bf(acc[d][4 * g + 2] * inv);
      o[3] = f2bf(acc[d][4 * g + 3] * inv);
      *(short4v*)(base + d * 32 + g * 8) = *(const short4v*)o;
    }
  }
}

// ---------------- launch ----------------

extern "C" void kernel_launch(void* const* d_in, const int* in_sizes, int n_in,
                              void* d_out, int out_size, void* d_ws, size_t ws_size,
                              hipStream_t stream) {
  int iq, ik, iv, im, iWq, ibq, iWk, ibk, iWv, ibv, iWo, ibo;
  if (in_sizes[0] == 8388608) {  // dict order: query first
    iq = 0; ik = 1; iv = 2; im = 3;
    iWq = 4; ibq = 5; iWk = 6; ibk = 7; iWv = 8; ibv = 9; iWo = 10; ibo = 11;
  } else {                        // alphabetical fallback
    iWk = 0; iWo = 1; iWq = 2; iWv = 3;
    ibk = 4; ibo = 5; ibq = 6; ibv = 7;
    ik = 8; im = 9; iq = 10; iv = 11;
  }
  const float* query = (const float*)d_in[iq];
  const float* key   = (const float*)d_in[ik];
  const float* value = (const float*)d_in[iv];
  const int*   mask  = (const int*)d_in[im];
  const float* Wq = (const float*)d_in[iWq];
  const float* bq = (const float*)d_in[ibq];
  const float* Wk = (const float*)d_in[iWk];
  const float* bk = (const float*)d_in[ibk];
  const float* Wv = (const float*)d_in[iWv];
  const float* bv = (const float*)d_in[ibv];
  const float* Wo = (const float*)d_in[iWo];
  const float* bo = (const float*)d_in[ibo];

  const long U  = 8388608;   // 4*2048*1024
  const long Wn = 1048576;   // 1024*1024
  u16* ws = (u16*)d_ws;
  u16* cq   = ws;            // bf16 query          16.8 MB
  u16* ck   = cq + U;        // bf16 key            16.8 MB
  u16* cv   = ck + U;        // bf16 value          16.8 MB
  u16* cWq  = cv + U;        // bf16 weights         2.1 MB x4
  u16* cWk  = cWq + Wn;
  u16* cWv  = cWk + Wn;
  u16* cWo  = cWv + Wn;
  u16* qws  = cWo + Wn;      // Q (b,h,s,dh)        16.8 MB
  u16* kws  = qws + U;       // K (b,h,s,dh)        16.8 MB
  u16* cws  = ck;            // alias: ck dead once attn runs (post-GEMMs)

  // Batched QKV needs V's output distinct from cq (Q-proj reads cq
  // concurrently). Take a fresh region if the workspace allows; else fall
  // back to the validated sequential path with vtws aliasing cq.
  const size_t need_batched = (size_t)(7 * U + 4 * Wn) * sizeof(u16);  // 109 MB
  const bool batched = ws_size >= need_batched;
  u16* vtws = batched ? (kws + U) : cq;   // V^T (b,h,dh,s)  16.8 MB

  const float C2F = 0.04508422f;  // log2(e)/32, folded into Q projection

  dim3 blk(256);

  CArgs ca;
  ca.in[0] = query; ca.out[0] = cq;  ca.n[0] = (int)U;
  ca.in[1] = key;   ca.out[1] = ck;  ca.n[1] = (int)U;
  ca.in[2] = value; ca.out[2] = cv;  ca.n[2] = (int)U;
  ca.in[3] = Wq;    ca.out[3] = cWq; ca.n[3] = (int)Wn;
  ca.in[4] = Wk;    ca.out[4] = cWk; ca.n[4] = (int)Wn;
  ca.in[5] = Wv;    ca.out[5] = cWv; ca.n[5] = (int)Wn;
  ca.in[6] = Wo;    ca.out[6] = cWo; ca.n[6] = (int)Wn;
  conv_bf16<<<dim3(4096, 7), blk, 0, stream>>>(ca);

  dim3 gproj(8, 64);  // N/128 x M/128
  if (batched) {
    G3 g3;
    g3.A[0] = cq; g3.W[0] = cWq; g3.bias[0] = bq; g3.C[0] = qws;  g3.mode[0] = 1; g3.oscale[0] = C2F;
    g3.A[1] = ck; g3.W[1] = cWk; g3.bias[1] = bk; g3.C[1] = kws;  g3.mode[1] = 1; g3.oscale[1] = 1.0f;
    g3.A[2] = cv; g3.W[2] = cWv; g3.bias[2] = bv; g3.C[2] = vtws; g3.mode[2] = 2; g3.oscale[2] = 1.0f;
    gemm_qkv<<<dim3(8, 64, 3), blk, 0, stream>>>(g3);
  } else {
    gemm_bt<false><<<gproj, blk, 0, stream>>>(cq, cWq, bq, qws, 8192, 1024, 1024, 1, C2F);
    gemm_bt<false><<<gproj, blk, 0, stream>>>(ck, cWk, bk, kws, 8192, 1024, 1024, 1, 1.0f);
    gemm_bt<false><<<gproj, blk, 0, stream>>>(cv, cWv, bv, vtws, 8192, 1024, 1024, 2, 1.0f);
  }
  attn<<<dim3(16, 64), blk, 0, stream>>>(qws, kws, vtws, mask, cws);
  gemm_bt<true><<<gproj, blk, 0, stream>>>(cws, cWo, bo, d_out, 8192, 1024, 1024, 0, 1.0f);
}